// Round 6
// baseline (633.481 us; speedup 1.0000x reference)
//
#include <hip/hip_runtime.h>
#include <math.h>

static constexpr int M_ROWS   = 200000;
static constexpr int NUM_NODE = 150;
static constexpr int ROW_F    = NUM_NODE * 4;     // 600 floats per row
static constexpr int BPR      = 4;                // rows per batch (pipeline depth)
static constexpr int NBATCH   = M_ROWS / BPR;     // 50000, exact
static constexpr int BLOCKS   = 2048;
static constexpr int WPB      = 4;                // waves per block
static constexpr int NWAVES   = BLOCKS * WPB;     // 8192
// batches per wave: ceil(50000/8192) = 7 (waves 0..848*... first 848? no: 50000 = 6*8192 + 848,
// so waves with wid < 848 get 7 batches, the rest get 6). MAX_ITERS = 7 bounds the loop.
static constexpr int MAX_ITERS = (NBATCH + NWAVES - 1) / NWAVES;   // 7

struct Batch {
    float4 c0[BPR], c1[BPR], c2[BPR];   // per-row node fragments (lane, lane+64, lane+128c)
    float  rx[BPR], ry[BPR];            // per-row obstacle position
};

__global__ __launch_bounds__(256) void obstacle_to_lane_kernel(
    const float* __restrict__ lf,       // (M, 150, 4) f32
    const float* __restrict__ obs_pos,  // (N, 2) f32
    const int*   __restrict__ mask,     // (M, 1) i32
    float*       __restrict__ out)      // [M*2 proj | M*2 idx | M*2 rep]
{
    const int wave = threadIdx.x >> 6;
    const int lane = threadIdx.x & 63;
    const int wid  = blockIdx.x * WPB + wave;     // 0..8191

    const int  j0   = lane;                                   // 0..63
    const int  j1   = lane + 64;                              // 64..127
    const int  j2c  = (lane + 128 < NUM_NODE) ? (lane + 128) : (NUM_NODE - 1);
    const bool a0ok = (lane >= 1);                            // argmin domain [1,148]
    const bool a2ok = (lane + 128 <= NUM_NODE - 2);           // lanes 0..20

    Batch A, B;

    // ---- issue one batch's loads: masks first, then 12 coalesced float4 row loads ----
    auto load = [&](Batch& b, int g) {
        int o[BPR];
        #pragma unroll
        for (int r = 0; r < BPR; ++r) o[r] = mask[g * BPR + r];
        const float* base = lf + (size_t)g * (BPR * ROW_F);
        #pragma unroll
        for (int r = 0; r < BPR; ++r) {
            const float* row = base + r * ROW_F;
            b.c0[r] = *reinterpret_cast<const float4*>(row + 4 * j0);
            b.c1[r] = *reinterpret_cast<const float4*>(row + 4 * j1);
            b.c2[r] = *reinterpret_cast<const float4*>(row + 4 * j2c);
        }
        #pragma unroll
        for (int r = 0; r < BPR; ++r) {
            b.rx[r] = obs_pos[2 * o[r]];
            b.ry[r] = obs_pos[2 * o[r] + 1];
        }
    };

    // ---- compute one batch (4 rows), r2's bit-verified math throughout ----
    auto compute = [&](const Batch& b, int g) {
        float bd[BPR];
        int   bj[BPR];
        #pragma unroll
        for (int r = 0; r < BPR; ++r) {
            bd[r] = INFINITY;
            bj[r] = 1 << 30;
            float dx, dy, d;
            dx = __fsub_rn(b.c0[r].x, b.rx[r]); dy = __fsub_rn(b.c0[r].y, b.ry[r]);
            d  = __fadd_rn(__fmul_rn(dx, dx), __fmul_rn(dy, dy));
            if (a0ok && d < bd[r]) { bd[r] = d; bj[r] = j0; }
            dx = __fsub_rn(b.c1[r].x, b.rx[r]); dy = __fsub_rn(b.c1[r].y, b.ry[r]);
            d  = __fadd_rn(__fmul_rn(dx, dx), __fmul_rn(dy, dy));
            if (d < bd[r]) { bd[r] = d; bj[r] = j1; }
            dx = __fsub_rn(b.c2[r].x, b.rx[r]); dy = __fsub_rn(b.c2[r].y, b.ry[r]);
            d  = __fadd_rn(__fmul_rn(dx, dx), __fmul_rn(dy, dy));
            if (a2ok && d < bd[r]) { bd[r] = d; bj[r] = lane + 128; }
        }
        // fused wave-wide argmin; ties -> smaller index (jnp.argmin semantics)
        #pragma unroll
        for (int off = 32; off > 0; off >>= 1) {
            #pragma unroll
            for (int r = 0; r < BPR; ++r) {
                const float od = __shfl_down(bd[r], off, 64);
                const int   oj = __shfl_down(bj[r], off, 64);
                if (od < bd[r] || (od == bd[r] && oj < bj[r])) { bd[r] = od; bj[r] = oj; }
            }
        }
        #pragma unroll
        for (int r = 0; r < BPR; ++r) {
            const int m       = g * BPR + r;
            const int min_idx = __shfl(bj[r], 0, 64);

            // neighbors via register shuffles; node q on lane (q&63), group (q>>6)
            auto pick = [&](int q) -> float4 {
                const int sl = q & 63;
                const int gg = q >> 6;                   // wave-uniform
                const float4 s = (gg == 0) ? b.c0[r] : ((gg == 1) ? b.c1[r] : b.c2[r]);
                float4 res;
                res.x = __shfl(s.x, sl, 64);
                res.y = __shfl(s.y, sl, 64);
                res.z = __shfl(s.z, sl, 64);
                res.w = __shfl(s.w, sl, 64);
                return res;
            };
            const float4 na = pick(min_idx - 1);
            const float4 nc = pick(min_idx);
            const float4 nb = pick(min_idx + 1);

            // dist_prev / dist_next, numpy left-to-right order, no FMA contraction
            float t, s;
            t = __fsub_rn(na.x, nc.x); s = __fmul_rn(t, t);
            t = __fsub_rn(na.y, nc.y); s = __fadd_rn(s, __fmul_rn(t, t));
            t = __fsub_rn(na.z, nc.z); s = __fadd_rn(s, __fmul_rn(t, t));
            t = __fsub_rn(na.w, nc.w); s = __fadd_rn(s, __fmul_rn(t, t));
            const float dist_prev = s;
            t = __fsub_rn(nb.x, nc.x); s = __fmul_rn(t, t);
            t = __fsub_rn(nb.y, nc.y); s = __fadd_rn(s, __fmul_rn(t, t));
            t = __fsub_rn(nb.z, nc.z); s = __fadd_rn(s, __fmul_rn(t, t));
            t = __fsub_rn(nb.w, nc.w); s = __fadd_rn(s, __fmul_rn(t, t));
            const float dist_next = s;

            float sx, sy, ex, ey;
            int ib;
            if (dist_next < dist_prev) {            // before=min_idx, after=min_idx+1
                ib = min_idx;     sx = nc.x; sy = nc.y; ex = nb.x; ey = nb.y;
            } else {                                // before=min_idx-1, after=min_idx
                ib = min_idx - 1; sx = na.x; sy = na.y; ex = nc.x; ey = nc.y;
            }

            const float lvx = __fsub_rn(ex, sx);
            const float lvy = __fsub_rn(ey, sy);
            const float mag = __fsqrt_rn(__fadd_rn(__fmul_rn(lvx, lvx), __fmul_rn(lvy, lvy)));
            const float ux  = __fdiv_rn(lvx, mag);
            const float uy  = __fdiv_rn(lvy, mag);
            const float pm  = __fadd_rn(__fmul_rn(__fsub_rn(b.rx[r], sx), ux),
                                        __fmul_rn(__fsub_rn(b.ry[r], sy), uy));
            const float px  = __fadd_rn(sx, __fmul_rn(pm, ux));
            const float py  = __fadd_rn(sy, __fmul_rn(pm, uy));

            if (lane < 3) {
                float2 v; size_t off;
                if (lane == 0)      { v = make_float2(px, py);                     off = 2 * (size_t)m; }
                else if (lane == 1) { v = make_float2((float)ib, (float)(ib + 1)); off = 2 * (size_t)M_ROWS + 2 * (size_t)m; }
                else                { v = make_float2(b.rx[r], b.ry[r]);           off = 4 * (size_t)M_ROWS + 2 * (size_t)m; }
                *reinterpret_cast<float2*>(out + off) = v;
            }
        }
    };

    // ---- bounded ping-pong pipeline: compute batch i while batch i+1 loads ----
    // wave wid owns batches {wid + k*NWAVES : k=0..6} (dense device-wide sliding
    // window; each batch = 9.6 KB contiguous).
    if (wid >= NBATCH) return;   // never true at these sizes; defensive
    load(A, wid);
    #pragma unroll 1
    for (int k = 0; k < MAX_ITERS; k += 2) {
        const int gA = wid + k * NWAVES;               // A holds gA (loaded)
        const int gB = gA + NWAVES;
        if (gB < NBATCH) load(B, gB);
        compute(A, gA);
        if (gB >= NBATCH) break;
        const int gA2 = gB + NWAVES;
        if (gA2 < NBATCH) load(A, gA2);
        compute(B, gB);
        if (gA2 >= NBATCH) break;
    }
}

extern "C" void kernel_launch(void* const* d_in, const int* in_sizes, int n_in,
                              void* d_out, int out_size, void* d_ws, size_t ws_size,
                              hipStream_t stream) {
    const float* lf      = (const float*)d_in[0];
    const float* obs_pos = (const float*)d_in[1];
    const int*   mask    = (const int*)d_in[2];
    float*       out     = (float*)d_out;

    hipLaunchKernelGGL(obstacle_to_lane_kernel, dim3(BLOCKS), dim3(256), 0, stream,
                       lf, obs_pos, mask, out);
}